// Round 7
// baseline (1394.636 us; speedup 1.0000x reference)
//
#include <hip/hip_runtime.h>
#include <math.h>
#include <limits.h>

#define NN 50000
#define NE 400000
#define FD 64
#define EDD 32
#define EPSF 1e-5f

// ---------------- degree / sort ----------------

__global__ void k_deg(const int* __restrict__ ei, int* __restrict__ cnt) {
    int e = blockIdx.x * 256 + threadIdx.x;
    if (e < NE) atomicAdd(&cnt[ei[NE + e]], 1);
}

__global__ void k_avglog(const int* __restrict__ cnt, float* __restrict__ scal) {
    int n = blockIdx.x * 256 + threadIdx.x;
    float v = 0.f;
    if (n < NN) v = logf((float)cnt[n] + 1.0f);
    for (int o = 32; o >= 1; o >>= 1) v += __shfl_xor(v, o);
    if ((threadIdx.x & 63) == 0) atomicAdd(&scal[0], v);
}

__global__ __launch_bounds__(1024) void k_scan(int* __restrict__ cnt, int* __restrict__ offv,
                                               float* __restrict__ scal) {
    __shared__ int buf[1024];
    __shared__ int carry;
    int tid = threadIdx.x;
    if (tid == 0) { carry = 0; scal[1] = scal[0] / (float)NN; }
    __syncthreads();
    for (int base = 0; base < NN; base += 1024) {
        int i = base + tid;
        int v = (i < NN) ? cnt[i] : 0;
        buf[tid] = v;
        __syncthreads();
        for (int s = 1; s < 1024; s <<= 1) {
            int t = (tid >= s) ? buf[tid - s] : 0;
            __syncthreads();
            buf[tid] += t;
            __syncthreads();
        }
        int incl = buf[tid];
        int excl = incl - v;
        if (i < NN) { offv[i] = carry + excl; cnt[i] = 0; }
        __syncthreads();
        if (tid == 0) carry += buf[1023];
        __syncthreads();
    }
    if (tid == 0) offv[NN] = carry;
}

// packs (src_row, edge_id) so k_edge does one uniform load per edge
__global__ void k_scatter(const int* __restrict__ ei, const int* __restrict__ offv,
                          int* __restrict__ cnt, int2* __restrict__ spair) {
    int e = blockIdx.x * 256 + threadIdx.x;
    if (e < NE) {
        int n = ei[NE + e];
        int p = offv[n] + atomicAdd(&cnt[n], 1);
        spair[p] = make_int2(ei[e], e);
    }
}

// amp/att per node (deg from offv, avg_log from scal[1])
__global__ void k_ampatt(const int* __restrict__ offv, const float* __restrict__ scal,
                         float* __restrict__ ampv, float* __restrict__ attv) {
    int n = blockIdx.x * 256 + threadIdx.x;
    if (n >= NN) return;
    float degf = (float)(offv[n + 1] - offv[n]);
    float d = fmaxf(degf, 1.f);
    float lg = logf(d + 1.f);
    float al = scal[1];
    ampv[n] = lg / al;
    attv[n] = al / lg;
}

// ---------------- per-layer kernels (single tower, T=1) ----------------

// weff[k*64 + g] = sum_f We[k][f] * Wee[f][g];  weff[32*64+g] = be @ Wee
__global__ void k_weff(const float* __restrict__ We, const float* __restrict__ be,
                       const float* __restrict__ preW, float* __restrict__ weff) {
    int idx = blockIdx.x * 256 + threadIdx.x;
    if (idx >= 33 * 64) return;
    int k = idx >> 6, g = idx & 63;
    const float* Wee = preW + 128 * 64;
    float acc = 0.f;
    if (k < EDD) {
        for (int f = 0; f < FD; ++f) acc += We[k * FD + f] * Wee[f * FD + g];
    } else {
        for (int f = 0; f < FD; ++f) acc += be[f] * Wee[f * FD + g];
    }
    weff[idx] = acc;
}

// u[n][g] = x[n] @ Wj col g ;  cvec[n][g] = x[n] @ Wi col g + preb[g] + beWee[g]
__global__ __launch_bounds__(256) void k_uc(const float* __restrict__ xin,
                                            const float* __restrict__ preW,
                                            const float* __restrict__ preb,
                                            const float* __restrict__ weff,
                                            float* __restrict__ u, float* __restrict__ cvec) {
    int g = threadIdx.x & 63;
    int nsub = threadIdx.x >> 6;
    float wU[FD], wC[FD];
#pragma unroll
    for (int f = 0; f < FD; ++f) {
        wC[f] = preW[f * 64 + g];
        wU[f] = preW[(64 + f) * 64 + g];
    }
    float cb = preb[g] + weff[32 * 64 + g];
    __shared__ float xs[4 * 72];
    for (int base = blockIdx.x * 4; base < NN; base += gridDim.x * 4) {
        __syncthreads();
        {
            int i = threadIdx.x;
            int node = base + (i >> 6);
            xs[(i >> 6) * 72 + (i & 63)] = (node < NN) ? xin[(size_t)node * 64 + (i & 63)] : 0.f;
        }
        __syncthreads();
        int n = base + nsub;
        if (n < NN) {
            const float* xv = &xs[nsub * 72];
            float aU = 0.f, aC = 0.f;
#pragma unroll
            for (int f = 0; f < FD; ++f) {
                float x = xv[f];
                aU += x * wU[f];
                aC += x * wC[f];
            }
            u[(size_t)n * 64 + g] = aU;
            cvec[(size_t)n * 64 + g] = aC + cb;
        }
    }
}

// sorted segment reduce, one wave per node; agg[n][stat*64+g], stats={mean,mn,mx,std}
__global__ __launch_bounds__(256) void k_edge(const float* __restrict__ eattr,
                                              const int* __restrict__ offv,
                                              const int2* __restrict__ spair,
                                              const float* __restrict__ u,
                                              const float* __restrict__ cvec,
                                              const float* __restrict__ weff,
                                              float* __restrict__ agg) {
    int wv = threadIdx.x >> 6, lane = threadIdx.x & 63;
    int n = blockIdx.x * 4 + wv;
    float wreg[32];
#pragma unroll
    for (int k = 0; k < 32; ++k) wreg[k] = weff[k * 64 + lane];
    int p0 = offv[n], p1 = offv[n + 1];
    float sm = 0.f, sq = 0.f, mn = INFINITY, mx = -INFINITY;
    for (int p = p0; p < p1; ++p) {
        int2 se = spair[p];
        int src = __builtin_amdgcn_readfirstlane(se.x);
        int eid = __builtin_amdgcn_readfirstlane(se.y);
        const float* __restrict__ ea = eattr + (size_t)eid * EDD;
        float v = u[(size_t)src * 64 + lane];
#pragma unroll
        for (int k = 0; k < 32; ++k) v += ea[k] * wreg[k];
        sm += v;
        sq += v * v;
        mn = fminf(mn, v);
        mx = fmaxf(mx, v);
    }
    float degf = (float)(p1 - p0);
    float d = fmaxf(degf, 1.f);
    float c = cvec[(size_t)n * 64 + lane];
    float sh = sm + degf * c;
    float mean = sh / d;
    float m2 = (sq + 2.f * c * sm + degf * c * c) / d;
    float var = fmaxf(m2 - mean * mean, 0.f);
    float sd = sqrtf(var + EPSF);
    float mnv = (degf > 0.f) ? mn + c : 0.f;
    float mxv = (degf > 0.f) ? mx + c : 0.f;
    size_t b = (size_t)n * 256 + lane;
    agg[b] = mean;
    agg[b + 64] = mnv;
    agg[b + 128] = mxv;
    agg[b + 192] = sd;
}

// ---------------- post stage: LDS-weight-stationary partial GEMMs ----------------
// z = [x(64) | agg(256) | amp*agg(256) | att*agg(256)], out = z @ P (832 x Gtot)
// Split by region into 3 kernels writing 3 partial buffers (summed in k_lin):
//   k_post0: tg0 = bias + x@P[0:64] + agg@P[64:320]     (20 KB LDS)
//   k_postS: tgX = scale[n] * (agg@P[rows 256 slice])    (16 KB LDS)
// Block: 128 threads, 4-lane column groups (16 cols/slice), NP=4 nodes/thread.
// Weight ds_reads are 4-distinct-address broadcasts -> conflict-free.
#define PNP 4

__global__ __launch_bounds__(128) void k_post0(const float* __restrict__ xin,
                                               const float* __restrict__ agg,
                                               const float* __restrict__ P,
                                               int pstride,
                                               const float* __restrict__ pbias,
                                               float* __restrict__ tg, int cb) {
    __shared__ __align__(16) float wsh[320 * 16];  // 20 KB
    int tid = threadIdx.x;
    int sc = blockIdx.y * 16;
    for (int i = tid; i < 320 * 4; i += 128) {
        int row = i >> 2, c4 = (i & 3) * 4;
        *(float4*)&wsh[row * 16 + c4] = *(const float4*)&P[(size_t)row * pstride + sc + c4];
    }
    __syncthreads();
    int cidx = (tid & 3) * 4;
    int grp = tid >> 2;  // 32 groups
    int nb = blockIdx.x * (32 * PNP) + grp * PNP;
    int nd[PNP];
#pragma unroll
    for (int k = 0; k < PNP; ++k) nd[k] = (nb + k < NN) ? nb + k : NN - 1;
    float acc[PNP][4];
#pragma unroll
    for (int k = 0; k < PNP; ++k)
#pragma unroll
        for (int c = 0; c < 4; ++c) acc[k][c] = 0.f;
    // x region: rows 0..63
#pragma unroll 4
    for (int q = 0; q < 64; q += 4) {
        float4 w[4];
#pragma unroll
        for (int r = 0; r < 4; ++r) w[r] = *(const float4*)&wsh[(q + r) * 16 + cidx];
#pragma unroll
        for (int k = 0; k < PNP; ++k) {
            float4 xv = *(const float4*)&xin[(size_t)nd[k] * 64 + q];
            float xa[4] = {xv.x, xv.y, xv.z, xv.w};
#pragma unroll
            for (int r = 0; r < 4; ++r) {
                acc[k][0] += xa[r] * w[r].x;
                acc[k][1] += xa[r] * w[r].y;
                acc[k][2] += xa[r] * w[r].z;
                acc[k][3] += xa[r] * w[r].w;
            }
        }
    }
    // agg region: rows 64..319 of panel, agg cols 0..255
#pragma unroll 4
    for (int q = 0; q < 256; q += 4) {
        float4 w[4];
#pragma unroll
        for (int r = 0; r < 4; ++r) w[r] = *(const float4*)&wsh[(64 + q + r) * 16 + cidx];
#pragma unroll
        for (int k = 0; k < PNP; ++k) {
            float4 av = *(const float4*)&agg[(size_t)nd[k] * 256 + q];
            float aa[4] = {av.x, av.y, av.z, av.w};
#pragma unroll
            for (int r = 0; r < 4; ++r) {
                acc[k][0] += aa[r] * w[r].x;
                acc[k][1] += aa[r] * w[r].y;
                acc[k][2] += aa[r] * w[r].z;
                acc[k][3] += aa[r] * w[r].w;
            }
        }
    }
    float4 pbv = *(const float4*)&pbias[sc + cidx];
#pragma unroll
    for (int k = 0; k < PNP; ++k) {
        int node = nb + k;
        if (node < NN) {
            float4 o = make_float4(acc[k][0] + pbv.x, acc[k][1] + pbv.y,
                                   acc[k][2] + pbv.z, acc[k][3] + pbv.w);
            *(float4*)&tg[(size_t)node * 64 + cb + sc + cidx] = o;
        }
    }
}

__global__ __launch_bounds__(128) void k_postS(const float* __restrict__ agg,
                                               const float* __restrict__ scalev,
                                               const float* __restrict__ P,  // pre-offset to region rows
                                               int pstride,
                                               float* __restrict__ tg, int cb) {
    __shared__ __align__(16) float wsh[256 * 16];  // 16 KB
    int tid = threadIdx.x;
    int sc = blockIdx.y * 16;
    for (int i = tid; i < 256 * 4; i += 128) {
        int row = i >> 2, c4 = (i & 3) * 4;
        *(float4*)&wsh[row * 16 + c4] = *(const float4*)&P[(size_t)row * pstride + sc + c4];
    }
    __syncthreads();
    int cidx = (tid & 3) * 4;
    int grp = tid >> 2;
    int nb = blockIdx.x * (32 * PNP) + grp * PNP;
    int nd[PNP];
    float sv[PNP];
#pragma unroll
    for (int k = 0; k < PNP; ++k) {
        nd[k] = (nb + k < NN) ? nb + k : NN - 1;
        sv[k] = scalev[nd[k]];
    }
    float acc[PNP][4];
#pragma unroll
    for (int k = 0; k < PNP; ++k)
#pragma unroll
        for (int c = 0; c < 4; ++c) acc[k][c] = 0.f;
#pragma unroll 4
    for (int q = 0; q < 256; q += 4) {
        float4 w[4];
#pragma unroll
        for (int r = 0; r < 4; ++r) w[r] = *(const float4*)&wsh[(q + r) * 16 + cidx];
#pragma unroll
        for (int k = 0; k < PNP; ++k) {
            float4 av = *(const float4*)&agg[(size_t)nd[k] * 256 + q];
            float aa[4] = {av.x, av.y, av.z, av.w};
#pragma unroll
            for (int r = 0; r < 4; ++r) {
                acc[k][0] += aa[r] * w[r].x;
                acc[k][1] += aa[r] * w[r].y;
                acc[k][2] += aa[r] * w[r].z;
                acc[k][3] += aa[r] * w[r].w;
            }
        }
    }
#pragma unroll
    for (int k = 0; k < PNP; ++k) {
        int node = nb + k;
        if (node < NN) {
            float4 o = make_float4(sv[k] * acc[k][0], sv[k] * acc[k][1],
                                   sv[k] * acc[k][2], sv[k] * acc[k][3]);
            *(float4*)&tg[(size_t)node * 64 + cb + sc + cidx] = o;
        }
    }
}

// pre = (tg0+tg1+tg2) @ linW + linb ; accumulate BN channel sums
__global__ __launch_bounds__(256) void k_lin(const float* __restrict__ tg0,
                                             const float* __restrict__ tg1,
                                             const float* __restrict__ tg2,
                                             const float* __restrict__ linW,
                                             const float* __restrict__ linb,
                                             float* __restrict__ pre, float* __restrict__ bn) {
    __shared__ float ts[4 * 72];
    __shared__ float rs[256], rs2[256];
    int c = threadIdx.x & 63, r = threadIdx.x >> 6;
    float w[64];
#pragma unroll
    for (int f = 0; f < 64; ++f) w[f] = linW[f * 64 + c];
    float lb = linb[c];
    float s = 0.f, s2 = 0.f;
    for (int base = blockIdx.x * 4; base < NN; base += gridDim.x * 4) {
        __syncthreads();
        {
            int i = threadIdx.x;
            int node = base + (i >> 6);
            size_t idx = (size_t)node * 64 + (i & 63);
            ts[(i >> 6) * 72 + (i & 63)] =
                (node < NN) ? (tg0[idx] + tg1[idx] + tg2[idx]) : 0.f;
        }
        __syncthreads();
        int n = base + r;
        if (n < NN) {
            const float* tv = &ts[r * 72];
            float a = lb;
#pragma unroll
            for (int f = 0; f < 64; ++f) a += tv[f] * w[f];
            pre[(size_t)n * 64 + c] = a;
            s += a;
            s2 += a * a;
        }
    }
    __syncthreads();
    rs[threadIdx.x] = s;
    rs2[threadIdx.x] = s2;
    __syncthreads();
    if (threadIdx.x < 64) {
        float S = rs[c] + rs[c + 64] + rs[c + 128] + rs[c + 192];
        float S2 = rs2[c] + rs2[c + 64] + rs2[c + 128] + rs2[c + 192];
        atomicAdd(&bn[c], S);
        atomicAdd(&bn[64 + c], S2);
    }
}

__global__ void k_bnrelu(const float* __restrict__ pre, const float* __restrict__ bn,
                         const float* __restrict__ gg, const float* __restrict__ bb,
                         float* __restrict__ h) {
    int i = blockIdx.x * 256 + threadIdx.x;
    if (i >= NN * 64) return;
    int c = i & 63;
    float m = bn[c] * (1.f / (float)NN);
    float v = bn[64 + c] * (1.f / (float)NN) - m * m;
    float x = (pre[i] - m) / sqrtf(v + EPSF) * gg[c] + bb[c];
    h[i] = fmaxf(x, 0.f);
}

// ---------------- pooling / topk / mlp ----------------

__global__ void k_pooldots(const float* __restrict__ h, const float* __restrict__ wrel,
                           const float* __restrict__ wroot, float* __restrict__ s1,
                           float* __restrict__ s2) {
    int wv = threadIdx.x >> 6, lane = threadIdx.x & 63;
    int n = blockIdx.x * 4 + wv;
    if (n >= NN) return;
    float x = h[(size_t)n * 64 + lane];
    float d1 = x * wrel[lane];
    float d2 = x * wroot[lane];
    for (int o = 32; o >= 1; o >>= 1) {
        d1 += __shfl_xor(d1, o);
        d2 += __shfl_xor(d2, o);
    }
    if (lane == 0) { s1[n] = d1; s2[n] = d2; }
}

__global__ void k_score(const float* __restrict__ s1, const float* __restrict__ s2,
                        const int* __restrict__ offv, const int2* __restrict__ spair,
                        const float* __restrict__ pb, float* __restrict__ score) {
    int n = blockIdx.x * 256 + threadIdx.x;
    if (n >= NN) return;
    float sc = pb[0] + s2[n];
    int p1 = offv[n + 1];
    for (int p = offv[n]; p < p1; ++p) sc += s1[spair[p].x];
    score[n] = sc;
}

#define TOPB 64
#define TOPCHUNK 782  // 64*782 >= 50000

__global__ __launch_bounds__(256) void k_top1(const float* __restrict__ score,
                                              float* __restrict__ candv, int* __restrict__ candi) {
    __shared__ float bs[256];
    __shared__ int bi[256];
    __shared__ int chosen[5];
    int b = blockIdx.x;
    int start = b * TOPCHUNK;
    int end = start + TOPCHUNK;
    if (end > NN) end = NN;
    for (int r = 0; r < 5; ++r) {
        float best = -INFINITY;
        int bidx = -1;
        for (int i = start + (int)threadIdx.x; i < end; i += 256) {
            bool skip = false;
            for (int q = 0; q < r; ++q)
                if (chosen[q] == i) skip = true;
            if (!skip) {
                float sv = score[i];
                if (sv > best || (sv == best && (bidx == -1 || i < bidx))) { best = sv; bidx = i; }
            }
        }
        bs[threadIdx.x] = best;
        bi[threadIdx.x] = bidx;
        __syncthreads();
        for (int s = 128; s >= 1; s >>= 1) {
            if ((int)threadIdx.x < s) {
                float s2v = bs[threadIdx.x + s];
                int i2 = bi[threadIdx.x + s];
                float s1v = bs[threadIdx.x];
                int i1 = bi[threadIdx.x];
                if (i2 != -1 && (s2v > s1v || (s2v == s1v && (i1 == -1 || i2 < i1)))) {
                    bs[threadIdx.x] = s2v;
                    bi[threadIdx.x] = i2;
                }
            }
            __syncthreads();
        }
        if (threadIdx.x == 0) {
            candv[b * 5 + r] = bs[0];
            candi[b * 5 + r] = bi[0];
            chosen[r] = bi[0];
        }
        __syncthreads();
    }
}

__global__ __launch_bounds__(320) void k_top2(const float* __restrict__ candv,
                                              const int* __restrict__ candi,
                                              float* __restrict__ topv, int* __restrict__ topi) {
    __shared__ float bs[320];
    __shared__ int bi[320];
    __shared__ int used[320];
    __shared__ float wbest[5];
    __shared__ int wnode[5], wpos[5];
    int tid = threadIdx.x;
    bs[tid] = candv[tid];
    bi[tid] = candi[tid];
    used[tid] = (bi[tid] == -1) ? 1 : 0;
    __syncthreads();
    int wv = tid >> 6, lane = tid & 63;
    for (int r = 0; r < 5; ++r) {
        float s = used[tid] ? -INFINITY : bs[tid];
        int nd = used[tid] ? INT_MAX : bi[tid];
        int pos = tid;
        for (int o = 32; o >= 1; o >>= 1) {
            float s2 = __shfl_xor(s, o);
            int nd2 = __shfl_xor(nd, o);
            int p2 = __shfl_xor(pos, o);
            if (s2 > s || (s2 == s && nd2 < nd)) { s = s2; nd = nd2; pos = p2; }
        }
        if (lane == 0) { wbest[wv] = s; wnode[wv] = nd; wpos[wv] = pos; }
        __syncthreads();
        if (tid == 0) {
            float best = wbest[0];
            int bnode = wnode[0], bpos = wpos[0];
            for (int i = 1; i < 5; ++i)
                if (wbest[i] > best || (wbest[i] == best && wnode[i] < bnode)) {
                    best = wbest[i];
                    bnode = wnode[i];
                    bpos = wpos[i];
                }
            used[bpos] = 1;
            topv[r] = best;
            topi[r] = bnode;
        }
        __syncthreads();
    }
}

__global__ __launch_bounds__(320) void k_mlp(const float* __restrict__ h,
                                             const float* __restrict__ topv,
                                             const int* __restrict__ topi,
                                             const float* __restrict__ mW1, const float* __restrict__ mb1,
                                             const float* __restrict__ mW2, const float* __restrict__ mb2,
                                             const float* __restrict__ mW3, const float* __restrict__ mb3,
                                             float* __restrict__ out) {
    __shared__ float xp[5 * 64], z1[5 * 32], z2[5 * 16];
    int tid = threadIdx.x;
    int k = tid >> 6, f = tid & 63;
    xp[k * 64 + f] = h[(size_t)topi[k] * 64 + f] * tanhf(topv[k]);
    __syncthreads();
    if (tid < 5 * 32) {
        int kk = tid >> 5, j = tid & 31;
        float a = mb1[j];
        for (int f2 = 0; f2 < 64; ++f2) a += xp[kk * 64 + f2] * mW1[f2 * 32 + j];
        z1[tid] = fmaxf(a, 0.f);
    }
    __syncthreads();
    if (tid < 5 * 16) {
        int kk = tid >> 4, j = tid & 15;
        float a = mb2[j];
        for (int f2 = 0; f2 < 32; ++f2) a += z1[kk * 32 + f2] * mW2[f2 * 16 + j];
        z2[tid] = fmaxf(a, 0.f);
    }
    __syncthreads();
    if (tid < 10) {
        int kk = tid >> 1, j = tid & 1;
        float a = mb3[j];
        for (int f2 = 0; f2 < 16; ++f2) a += z2[kk * 16 + f2] * mW3[f2 * 2 + j];
        out[tid] = a;
    }
}

// ---------------- host ----------------

extern "C" void kernel_launch(void* const* d_in, const int* in_sizes, int n_in,
                              void* d_out, int out_size, void* d_ws, size_t ws_size,
                              hipStream_t stream) {
    const float* x = (const float*)d_in[0];
    const int* ei = (const int*)d_in[1];
    const float* eattr = (const float*)d_in[2];
    const float* We1 = (const float*)d_in[4];
    const float* be1 = (const float*)d_in[5];
    const float* preW1 = (const float*)d_in[6];
    const float* preb1 = (const float*)d_in[7];
    const float* postW1 = (const float*)d_in[8];
    const float* postb1 = (const float*)d_in[9];
    const float* linW1 = (const float*)d_in[10];
    const float* linb1 = (const float*)d_in[11];
    const float* bn1g = (const float*)d_in[12];
    const float* bn1b = (const float*)d_in[13];
    const float* We2 = (const float*)d_in[14];
    const float* be2 = (const float*)d_in[15];
    const float* preW2 = (const float*)d_in[16];
    const float* preb2 = (const float*)d_in[17];
    const float* postW2 = (const float*)d_in[18];
    const float* postb2 = (const float*)d_in[19];
    const float* linW2 = (const float*)d_in[20];
    const float* linb2 = (const float*)d_in[21];
    const float* bn2g = (const float*)d_in[22];
    const float* bn2b = (const float*)d_in[23];
    const float* wrel = (const float*)d_in[24];
    const float* pbrel = (const float*)d_in[25];
    const float* wroot = (const float*)d_in[26];
    const float* mW1 = (const float*)d_in[27];
    const float* mb1 = (const float*)d_in[28];
    const float* mW2 = (const float*)d_in[29];
    const float* mb2 = (const float*)d_in[30];
    const float* mW3 = (const float*)d_in[31];
    const float* mb3 = (const float*)d_in[32];
    float* out = (float*)d_out;

    char* w = (char*)d_ws;
    size_t o = 0;
    auto alloc = [&](size_t bytes) {
        size_t r = o;
        o = (o + bytes + 255) & ~(size_t)255;
        return r;
    };
    int* cnt = (int*)(w + alloc((size_t)NN * 4));
    int* offv = (int*)(w + alloc((size_t)(NN + 1) * 4));
    int2* spair = (int2*)(w + alloc((size_t)NE * 8));
    float* scal = (float*)(w + alloc(64 * 4));
    float* bnst = (float*)(w + alloc(128 * 4));
    float* weff = (float*)(w + alloc((size_t)33 * 64 * 4));
    float* ampv = (float*)(w + alloc((size_t)NN * 4));
    float* attv = (float*)(w + alloc((size_t)NN * 4));
    float* u = (float*)(w + alloc((size_t)NN * 64 * 4));
    float* cvec = (float*)(w + alloc((size_t)NN * 64 * 4));
    float* agg = (float*)(w + alloc((size_t)NN * 256 * 4));
    float* tg0 = (float*)(w + alloc((size_t)NN * 64 * 4));
    float* tg1 = (float*)(w + alloc((size_t)NN * 64 * 4));
    float* tg2 = (float*)(w + alloc((size_t)NN * 64 * 4));
    float* pre = (float*)(w + alloc((size_t)NN * 64 * 4));
    float* h1 = (float*)(w + alloc((size_t)NN * 64 * 4));
    float* h2 = (float*)(w + alloc((size_t)NN * 64 * 4));
    float* s1 = (float*)(w + alloc((size_t)NN * 4));
    float* s2 = (float*)(w + alloc((size_t)NN * 4));
    float* score = (float*)(w + alloc((size_t)NN * 4));
    float* candv = (float*)(w + alloc(320 * 4));
    int* candi = (int*)(w + alloc(320 * 4));
    float* topv = (float*)(w + alloc(16 * 4));
    int* topi = (int*)(w + alloc(16 * 4));
    (void)ws_size; (void)n_in; (void)in_sizes; (void)out_size;

    hipMemsetAsync(cnt, 0, (size_t)NN * 4, stream);
    hipMemsetAsync(scal, 0, 64 * 4, stream);

    k_deg<<<(NE + 255) / 256, 256, 0, stream>>>(ei, cnt);
    k_avglog<<<(NN + 255) / 256, 256, 0, stream>>>(cnt, scal);
    k_scan<<<1, 1024, 0, stream>>>(cnt, offv, scal);
    k_scatter<<<(NE + 255) / 256, 256, 0, stream>>>(ei, offv, cnt, spair);
    k_ampatt<<<(NN + 255) / 256, 256, 0, stream>>>(offv, scal, ampv, attv);

    int ptiles = (NN + 32 * PNP - 1) / (32 * PNP);  // 391

    // ---- layer 1 (G=64 -> 4 col slices via gridDim.y) ----
    k_weff<<<(33 * 64 + 255) / 256, 256, 0, stream>>>(We1, be1, preW1, weff);
    k_uc<<<500, 256, 0, stream>>>(x, preW1, preb1, weff, u, cvec);
    k_edge<<<NN / 4, 256, 0, stream>>>(eattr, offv, spair, u, cvec, weff, agg);
    k_post0<<<dim3(ptiles, 4), 128, 0, stream>>>(x, agg, postW1, 64, postb1, tg0, 0);
    k_postS<<<dim3(ptiles, 4), 128, 0, stream>>>(agg, ampv, postW1 + 320 * 64, 64, tg1, 0);
    k_postS<<<dim3(ptiles, 4), 128, 0, stream>>>(agg, attv, postW1 + 576 * 64, 64, tg2, 0);
    hipMemsetAsync(bnst, 0, 128 * 4, stream);
    k_lin<<<256, 256, 0, stream>>>(tg0, tg1, tg2, linW1, linb1, pre, bnst);
    k_bnrelu<<<(NN * 64) / 256, 256, 0, stream>>>(pre, bnst, bn1g, bn1b, h1);

    // ---- layer 2 (4 towers, each writes cols t*16..t*16+15 of tg0/1/2) ----
    for (int t = 0; t < 4; ++t) {
        const float* pW = preW2 + (size_t)t * 192 * 64;
        const float* pP = postW2 + (size_t)t * 832 * 16;
        k_weff<<<(33 * 64 + 255) / 256, 256, 0, stream>>>(We2, be2, pW, weff);
        k_uc<<<500, 256, 0, stream>>>(h1, pW, preb2 + t * 64, weff, u, cvec);
        k_edge<<<NN / 4, 256, 0, stream>>>(eattr, offv, spair, u, cvec, weff, agg);
        k_post0<<<dim3(ptiles, 1), 128, 0, stream>>>(h1, agg, pP, 16, postb2 + t * 16, tg0, t * 16);
        k_postS<<<dim3(ptiles, 1), 128, 0, stream>>>(agg, ampv, pP + 320 * 16, 16, tg1, t * 16);
        k_postS<<<dim3(ptiles, 1), 128, 0, stream>>>(agg, attv, pP + 576 * 16, 16, tg2, t * 16);
    }
    hipMemsetAsync(bnst, 0, 128 * 4, stream);
    k_lin<<<256, 256, 0, stream>>>(tg0, tg1, tg2, linW2, linb2, pre, bnst);
    k_bnrelu<<<(NN * 64) / 256, 256, 0, stream>>>(pre, bnst, bn2g, bn2b, h2);

    // ---- pooling / topk / mlp ----
    k_pooldots<<<NN / 4, 256, 0, stream>>>(h2, wrel, wroot, s1, s2);
    k_score<<<(NN + 255) / 256, 256, 0, stream>>>(s1, s2, offv, spair, pbrel, score);
    k_top1<<<TOPB, 256, 0, stream>>>(score, candv, candi);
    k_top2<<<1, 320, 0, stream>>>(candv, candi, topv, topi);
    k_mlp<<<1, 320, 0, stream>>>(h2, topv, topi, mW1, mb1, mW2, mb2, mW3, mb3, out);
}

// Round 8
// 1263.652 us; speedup vs baseline: 1.1037x; 1.1037x over previous
//
#include <hip/hip_runtime.h>
#include <math.h>
#include <limits.h>

#define NN 50000
#define NE 400000
#define FD 64
#define EDD 32
#define EPSF 1e-5f

// ---------------- degree / sort ----------------

__global__ void k_deg(const int* __restrict__ ei, int* __restrict__ cnt) {
    int e = blockIdx.x * 256 + threadIdx.x;
    if (e < NE) atomicAdd(&cnt[ei[NE + e]], 1);
}

__global__ void k_avglog(const int* __restrict__ cnt, float* __restrict__ scal) {
    int n = blockIdx.x * 256 + threadIdx.x;
    float v = 0.f;
    if (n < NN) v = logf((float)cnt[n] + 1.0f);
    for (int o = 32; o >= 1; o >>= 1) v += __shfl_xor(v, o);
    if ((threadIdx.x & 63) == 0) atomicAdd(&scal[0], v);
}

// 3-phase parallel exclusive scan of cnt -> offv (replaces 92us single-block scan)
__global__ __launch_bounds__(256) void k_scan1(const int* __restrict__ cnt,
                                               int* __restrict__ part, int* __restrict__ bsum) {
    __shared__ int buf[256];
    int i = blockIdx.x * 256 + threadIdx.x;
    int v = (i < NN) ? cnt[i] : 0;
    buf[threadIdx.x] = v;
    __syncthreads();
    for (int s = 1; s < 256; s <<= 1) {
        int t = (threadIdx.x >= (unsigned)s) ? buf[threadIdx.x - s] : 0;
        __syncthreads();
        buf[threadIdx.x] += t;
        __syncthreads();
    }
    if (i < NN) part[i] = buf[threadIdx.x] - v;  // exclusive within block
    if (threadIdx.x == 255) bsum[blockIdx.x] = buf[255];
}

__global__ __launch_bounds__(256) void k_scan2(const int* __restrict__ bsum,
                                               int* __restrict__ boff,
                                               float* __restrict__ scal, int nb) {
    __shared__ int buf[256];
    int tid = threadIdx.x;
    int v = (tid < nb) ? bsum[tid] : 0;
    buf[tid] = v;
    __syncthreads();
    for (int s = 1; s < 256; s <<= 1) {
        int t = (tid >= s) ? buf[tid - s] : 0;
        __syncthreads();
        buf[tid] += t;
        __syncthreads();
    }
    boff[tid] = buf[tid] - v;
    if (tid == nb - 1) boff[nb] = buf[tid];
    if (tid == 0) scal[1] = scal[0] / (float)NN;
}

__global__ void k_scan3(const int* __restrict__ part, const int* __restrict__ boff,
                        int* __restrict__ offv, int* __restrict__ cnt) {
    int i = blockIdx.x * 256 + threadIdx.x;
    if (i < NN) {
        offv[i] = part[i] + boff[blockIdx.x];
        cnt[i] = 0;
    }
    if (i == 0) offv[NN] = boff[gridDim.x];
}

// packs (src_row, edge_id) so k_edge does one uniform load per edge
__global__ void k_scatter(const int* __restrict__ ei, const int* __restrict__ offv,
                          int* __restrict__ cnt, int2* __restrict__ spair) {
    int e = blockIdx.x * 256 + threadIdx.x;
    if (e < NE) {
        int n = ei[NE + e];
        int p = offv[n] + atomicAdd(&cnt[n], 1);
        spair[p] = make_int2(ei[e], e);
    }
}

// amp/att per node (deg from offv, avg_log from scal[1])
__global__ void k_ampatt(const int* __restrict__ offv, const float* __restrict__ scal,
                         float* __restrict__ ampv, float* __restrict__ attv) {
    int n = blockIdx.x * 256 + threadIdx.x;
    if (n >= NN) return;
    float degf = (float)(offv[n + 1] - offv[n]);
    float d = fmaxf(degf, 1.f);
    float lg = logf(d + 1.f);
    float al = scal[1];
    ampv[n] = lg / al;
    attv[n] = al / lg;
}

// ---------------- per-layer kernels (single tower, T=1) ----------------

// weff[k*64 + g] = sum_f We[k][f] * Wee[f][g];  weff[32*64+g] = be @ Wee
__global__ void k_weff(const float* __restrict__ We, const float* __restrict__ be,
                       const float* __restrict__ preW, float* __restrict__ weff) {
    int idx = blockIdx.x * 256 + threadIdx.x;
    if (idx >= 33 * 64) return;
    int k = idx >> 6, g = idx & 63;
    const float* Wee = preW + 128 * 64;
    float acc = 0.f;
    if (k < EDD) {
        for (int f = 0; f < FD; ++f) acc += We[k * FD + f] * Wee[f * FD + g];
    } else {
        for (int f = 0; f < FD; ++f) acc += be[f] * Wee[f * FD + g];
    }
    weff[idx] = acc;
}

// u[n][g] = x[n] @ Wj col g ;  cvec[n][g] = x[n] @ Wi col g + preb[g] + beWee[g]
__global__ __launch_bounds__(256) void k_uc(const float* __restrict__ xin,
                                            const float* __restrict__ preW,
                                            const float* __restrict__ preb,
                                            const float* __restrict__ weff,
                                            float* __restrict__ u, float* __restrict__ cvec) {
    int g = threadIdx.x & 63;
    int nsub = threadIdx.x >> 6;
    float wU[FD], wC[FD];
#pragma unroll
    for (int f = 0; f < FD; ++f) {
        wC[f] = preW[f * 64 + g];
        wU[f] = preW[(64 + f) * 64 + g];
    }
    float cb = preb[g] + weff[32 * 64 + g];
    __shared__ float xs[4 * 72];
    for (int base = blockIdx.x * 4; base < NN; base += gridDim.x * 4) {
        __syncthreads();
        {
            int i = threadIdx.x;
            int node = base + (i >> 6);
            xs[(i >> 6) * 72 + (i & 63)] = (node < NN) ? xin[(size_t)node * 64 + (i & 63)] : 0.f;
        }
        __syncthreads();
        int n = base + nsub;
        if (n < NN) {
            const float* xv = &xs[nsub * 72];
            float aU = 0.f, aC = 0.f;
#pragma unroll
            for (int f = 0; f < FD; ++f) {
                float x = xv[f];
                aU += x * wU[f];
                aC += x * wC[f];
            }
            u[(size_t)n * 64 + g] = aU;
            cvec[(size_t)n * 64 + g] = aC + cb;
        }
    }
}

// sorted segment reduce, one wave per node; agg[n][stat*64+g], stats={mean,mn,mx,std}
// Unrolled by 2 edges so two independent scalar-load chains pipeline.
// FP accumulation order preserved (v0 then v1, sequential).
__global__ __launch_bounds__(256) void k_edge(const float* __restrict__ eattr,
                                              const int* __restrict__ offv,
                                              const int2* __restrict__ spair,
                                              const float* __restrict__ u,
                                              const float* __restrict__ cvec,
                                              const float* __restrict__ weff,
                                              float* __restrict__ agg) {
    int wv = threadIdx.x >> 6, lane = threadIdx.x & 63;
    int n = blockIdx.x * 4 + wv;
    float wreg[32];
#pragma unroll
    for (int k = 0; k < 32; ++k) wreg[k] = weff[k * 64 + lane];
    int p0 = offv[n], p1 = offv[n + 1];
    float sm = 0.f, sq = 0.f, mn = INFINITY, mx = -INFINITY;
    int p = p0;
    for (; p + 1 < p1; p += 2) {
        int2 se0 = spair[p];
        int2 se1 = spair[p + 1];
        int src0 = __builtin_amdgcn_readfirstlane(se0.x);
        int eid0 = __builtin_amdgcn_readfirstlane(se0.y);
        int src1 = __builtin_amdgcn_readfirstlane(se1.x);
        int eid1 = __builtin_amdgcn_readfirstlane(se1.y);
        const float* __restrict__ ea0 = eattr + (size_t)eid0 * EDD;
        const float* __restrict__ ea1 = eattr + (size_t)eid1 * EDD;
        float v0 = u[(size_t)src0 * 64 + lane];
        float v1 = u[(size_t)src1 * 64 + lane];
#pragma unroll
        for (int k = 0; k < 32; ++k) {
            v0 += ea0[k] * wreg[k];
            v1 += ea1[k] * wreg[k];
        }
        sm += v0;
        sq += v0 * v0;
        mn = fminf(mn, v0);
        mx = fmaxf(mx, v0);
        sm += v1;
        sq += v1 * v1;
        mn = fminf(mn, v1);
        mx = fmaxf(mx, v1);
    }
    if (p < p1) {
        int2 se = spair[p];
        int src = __builtin_amdgcn_readfirstlane(se.x);
        int eid = __builtin_amdgcn_readfirstlane(se.y);
        const float* __restrict__ ea = eattr + (size_t)eid * EDD;
        float v = u[(size_t)src * 64 + lane];
#pragma unroll
        for (int k = 0; k < 32; ++k) v += ea[k] * wreg[k];
        sm += v;
        sq += v * v;
        mn = fminf(mn, v);
        mx = fmaxf(mx, v);
    }
    float degf = (float)(p1 - p0);
    float d = fmaxf(degf, 1.f);
    float c = cvec[(size_t)n * 64 + lane];
    float sh = sm + degf * c;
    float mean = sh / d;
    float m2 = (sq + 2.f * c * sm + degf * c * c) / d;
    float var = fmaxf(m2 - mean * mean, 0.f);
    float sd = sqrtf(var + EPSF);
    float mnv = (degf > 0.f) ? mn + c : 0.f;
    float mxv = (degf > 0.f) ? mx + c : 0.f;
    size_t b = (size_t)n * 256 + lane;
    agg[b] = mean;
    agg[b + 64] = mnv;
    agg[b + 128] = mxv;
    agg[b + 192] = sd;
}

// ---------------- post stage: LDS-weight-stationary partial GEMMs ----------------
#define PNP 4

__global__ __launch_bounds__(128) void k_post0(const float* __restrict__ xin,
                                               const float* __restrict__ agg,
                                               const float* __restrict__ P,
                                               int pstride,
                                               const float* __restrict__ pbias,
                                               float* __restrict__ tg, int cb) {
    __shared__ __align__(16) float wsh[320 * 16];  // 20 KB
    int tid = threadIdx.x;
    int sc = blockIdx.y * 16;
    for (int i = tid; i < 320 * 4; i += 128) {
        int row = i >> 2, c4 = (i & 3) * 4;
        *(float4*)&wsh[row * 16 + c4] = *(const float4*)&P[(size_t)row * pstride + sc + c4];
    }
    __syncthreads();
    int cidx = (tid & 3) * 4;
    int grp = tid >> 2;  // 32 groups
    int nb = blockIdx.x * (32 * PNP) + grp * PNP;
    int nd[PNP];
#pragma unroll
    for (int k = 0; k < PNP; ++k) nd[k] = (nb + k < NN) ? nb + k : NN - 1;
    float acc[PNP][4];
#pragma unroll
    for (int k = 0; k < PNP; ++k)
#pragma unroll
        for (int c = 0; c < 4; ++c) acc[k][c] = 0.f;
#pragma unroll 4
    for (int q = 0; q < 64; q += 4) {
        float4 w[4];
#pragma unroll
        for (int r = 0; r < 4; ++r) w[r] = *(const float4*)&wsh[(q + r) * 16 + cidx];
#pragma unroll
        for (int k = 0; k < PNP; ++k) {
            float4 xv = *(const float4*)&xin[(size_t)nd[k] * 64 + q];
            float xa[4] = {xv.x, xv.y, xv.z, xv.w};
#pragma unroll
            for (int r = 0; r < 4; ++r) {
                acc[k][0] += xa[r] * w[r].x;
                acc[k][1] += xa[r] * w[r].y;
                acc[k][2] += xa[r] * w[r].z;
                acc[k][3] += xa[r] * w[r].w;
            }
        }
    }
#pragma unroll 4
    for (int q = 0; q < 256; q += 4) {
        float4 w[4];
#pragma unroll
        for (int r = 0; r < 4; ++r) w[r] = *(const float4*)&wsh[(64 + q + r) * 16 + cidx];
#pragma unroll
        for (int k = 0; k < PNP; ++k) {
            float4 av = *(const float4*)&agg[(size_t)nd[k] * 256 + q];
            float aa[4] = {av.x, av.y, av.z, av.w};
#pragma unroll
            for (int r = 0; r < 4; ++r) {
                acc[k][0] += aa[r] * w[r].x;
                acc[k][1] += aa[r] * w[r].y;
                acc[k][2] += aa[r] * w[r].z;
                acc[k][3] += aa[r] * w[r].w;
            }
        }
    }
    float4 pbv = *(const float4*)&pbias[sc + cidx];
#pragma unroll
    for (int k = 0; k < PNP; ++k) {
        int node = nb + k;
        if (node < NN) {
            float4 o = make_float4(acc[k][0] + pbv.x, acc[k][1] + pbv.y,
                                   acc[k][2] + pbv.z, acc[k][3] + pbv.w);
            *(float4*)&tg[(size_t)node * 64 + cb + sc + cidx] = o;
        }
    }
}

__global__ __launch_bounds__(128) void k_postS(const float* __restrict__ agg,
                                               const float* __restrict__ scalev,
                                               const float* __restrict__ P,
                                               int pstride,
                                               float* __restrict__ tg, int cb) {
    __shared__ __align__(16) float wsh[256 * 16];  // 16 KB
    int tid = threadIdx.x;
    int sc = blockIdx.y * 16;
    for (int i = tid; i < 256 * 4; i += 128) {
        int row = i >> 2, c4 = (i & 3) * 4;
        *(float4*)&wsh[row * 16 + c4] = *(const float4*)&P[(size_t)row * pstride + sc + c4];
    }
    __syncthreads();
    int cidx = (tid & 3) * 4;
    int grp = tid >> 2;
    int nb = blockIdx.x * (32 * PNP) + grp * PNP;
    int nd[PNP];
    float sv[PNP];
#pragma unroll
    for (int k = 0; k < PNP; ++k) {
        nd[k] = (nb + k < NN) ? nb + k : NN - 1;
        sv[k] = scalev[nd[k]];
    }
    float acc[PNP][4];
#pragma unroll
    for (int k = 0; k < PNP; ++k)
#pragma unroll
        for (int c = 0; c < 4; ++c) acc[k][c] = 0.f;
#pragma unroll 4
    for (int q = 0; q < 256; q += 4) {
        float4 w[4];
#pragma unroll
        for (int r = 0; r < 4; ++r) w[r] = *(const float4*)&wsh[(q + r) * 16 + cidx];
#pragma unroll
        for (int k = 0; k < PNP; ++k) {
            float4 av = *(const float4*)&agg[(size_t)nd[k] * 256 + q];
            float aa[4] = {av.x, av.y, av.z, av.w};
#pragma unroll
            for (int r = 0; r < 4; ++r) {
                acc[k][0] += aa[r] * w[r].x;
                acc[k][1] += aa[r] * w[r].y;
                acc[k][2] += aa[r] * w[r].z;
                acc[k][3] += aa[r] * w[r].w;
            }
        }
    }
#pragma unroll
    for (int k = 0; k < PNP; ++k) {
        int node = nb + k;
        if (node < NN) {
            float4 o = make_float4(sv[k] * acc[k][0], sv[k] * acc[k][1],
                                   sv[k] * acc[k][2], sv[k] * acc[k][3]);
            *(float4*)&tg[(size_t)node * 64 + cb + sc + cidx] = o;
        }
    }
}

// pre = (tg0+tg1+tg2) @ linW + linb ; accumulate BN channel sums
__global__ __launch_bounds__(256) void k_lin(const float* __restrict__ tg0,
                                             const float* __restrict__ tg1,
                                             const float* __restrict__ tg2,
                                             const float* __restrict__ linW,
                                             const float* __restrict__ linb,
                                             float* __restrict__ pre, float* __restrict__ bn) {
    __shared__ float ts[4 * 72];
    __shared__ float rs[256], rs2[256];
    int c = threadIdx.x & 63, r = threadIdx.x >> 6;
    float w[64];
#pragma unroll
    for (int f = 0; f < 64; ++f) w[f] = linW[f * 64 + c];
    float lb = linb[c];
    float s = 0.f, s2 = 0.f;
    for (int base = blockIdx.x * 4; base < NN; base += gridDim.x * 4) {
        __syncthreads();
        {
            int i = threadIdx.x;
            int node = base + (i >> 6);
            size_t idx = (size_t)node * 64 + (i & 63);
            ts[(i >> 6) * 72 + (i & 63)] =
                (node < NN) ? (tg0[idx] + tg1[idx] + tg2[idx]) : 0.f;
        }
        __syncthreads();
        int n = base + r;
        if (n < NN) {
            const float* tv = &ts[r * 72];
            float a = lb;
#pragma unroll
            for (int f = 0; f < 64; ++f) a += tv[f] * w[f];
            pre[(size_t)n * 64 + c] = a;
            s += a;
            s2 += a * a;
        }
    }
    __syncthreads();
    rs[threadIdx.x] = s;
    rs2[threadIdx.x] = s2;
    __syncthreads();
    if (threadIdx.x < 64) {
        float S = rs[c] + rs[c + 64] + rs[c + 128] + rs[c + 192];
        float S2 = rs2[c] + rs2[c + 64] + rs2[c + 128] + rs2[c + 192];
        atomicAdd(&bn[c], S);
        atomicAdd(&bn[64 + c], S2);
    }
}

__global__ void k_bnrelu(const float* __restrict__ pre, const float* __restrict__ bn,
                         const float* __restrict__ gg, const float* __restrict__ bb,
                         float* __restrict__ h) {
    int i = blockIdx.x * 256 + threadIdx.x;
    if (i >= NN * 64) return;
    int c = i & 63;
    float m = bn[c] * (1.f / (float)NN);
    float v = bn[64 + c] * (1.f / (float)NN) - m * m;
    float x = (pre[i] - m) / sqrtf(v + EPSF) * gg[c] + bb[c];
    h[i] = fmaxf(x, 0.f);
}

// ---------------- pooling / topk / mlp ----------------

__global__ void k_pooldots(const float* __restrict__ h, const float* __restrict__ wrel,
                           const float* __restrict__ wroot, float* __restrict__ s1,
                           float* __restrict__ s2) {
    int wv = threadIdx.x >> 6, lane = threadIdx.x & 63;
    int n = blockIdx.x * 4 + wv;
    if (n >= NN) return;
    float x = h[(size_t)n * 64 + lane];
    float d1 = x * wrel[lane];
    float d2 = x * wroot[lane];
    for (int o = 32; o >= 1; o >>= 1) {
        d1 += __shfl_xor(d1, o);
        d2 += __shfl_xor(d2, o);
    }
    if (lane == 0) { s1[n] = d1; s2[n] = d2; }
}

__global__ void k_score(const float* __restrict__ s1, const float* __restrict__ s2,
                        const int* __restrict__ offv, const int2* __restrict__ spair,
                        const float* __restrict__ pb, float* __restrict__ score) {
    int n = blockIdx.x * 256 + threadIdx.x;
    if (n >= NN) return;
    float sc = pb[0] + s2[n];
    int p1 = offv[n + 1];
    for (int p = offv[n]; p < p1; ++p) sc += s1[spair[p].x];
    score[n] = sc;
}

#define TOPB 64
#define TOPCHUNK 782  // 64*782 >= 50000

__global__ __launch_bounds__(256) void k_top1(const float* __restrict__ score,
                                              float* __restrict__ candv, int* __restrict__ candi) {
    __shared__ float bs[256];
    __shared__ int bi[256];
    __shared__ int chosen[5];
    int b = blockIdx.x;
    int start = b * TOPCHUNK;
    int end = start + TOPCHUNK;
    if (end > NN) end = NN;
    for (int r = 0; r < 5; ++r) {
        float best = -INFINITY;
        int bidx = -1;
        for (int i = start + (int)threadIdx.x; i < end; i += 256) {
            bool skip = false;
            for (int q = 0; q < r; ++q)
                if (chosen[q] == i) skip = true;
            if (!skip) {
                float sv = score[i];
                if (sv > best || (sv == best && (bidx == -1 || i < bidx))) { best = sv; bidx = i; }
            }
        }
        bs[threadIdx.x] = best;
        bi[threadIdx.x] = bidx;
        __syncthreads();
        for (int s = 128; s >= 1; s >>= 1) {
            if ((int)threadIdx.x < s) {
                float s2v = bs[threadIdx.x + s];
                int i2 = bi[threadIdx.x + s];
                float s1v = bs[threadIdx.x];
                int i1 = bi[threadIdx.x];
                if (i2 != -1 && (s2v > s1v || (s2v == s1v && (i1 == -1 || i2 < i1)))) {
                    bs[threadIdx.x] = s2v;
                    bi[threadIdx.x] = i2;
                }
            }
            __syncthreads();
        }
        if (threadIdx.x == 0) {
            candv[b * 5 + r] = bs[0];
            candi[b * 5 + r] = bi[0];
            chosen[r] = bi[0];
        }
        __syncthreads();
    }
}

__global__ __launch_bounds__(320) void k_top2(const float* __restrict__ candv,
                                              const int* __restrict__ candi,
                                              float* __restrict__ topv, int* __restrict__ topi) {
    __shared__ float bs[320];
    __shared__ int bi[320];
    __shared__ int used[320];
    __shared__ float wbest[5];
    __shared__ int wnode[5], wpos[5];
    int tid = threadIdx.x;
    bs[tid] = candv[tid];
    bi[tid] = candi[tid];
    used[tid] = (bi[tid] == -1) ? 1 : 0;
    __syncthreads();
    int wv = tid >> 6, lane = tid & 63;
    for (int r = 0; r < 5; ++r) {
        float s = used[tid] ? -INFINITY : bs[tid];
        int nd = used[tid] ? INT_MAX : bi[tid];
        int pos = tid;
        for (int o = 32; o >= 1; o >>= 1) {
            float s2 = __shfl_xor(s, o);
            int nd2 = __shfl_xor(nd, o);
            int p2 = __shfl_xor(pos, o);
            if (s2 > s || (s2 == s && nd2 < nd)) { s = s2; nd = nd2; pos = p2; }
        }
        if (lane == 0) { wbest[wv] = s; wnode[wv] = nd; wpos[wv] = pos; }
        __syncthreads();
        if (tid == 0) {
            float best = wbest[0];
            int bnode = wnode[0], bpos = wpos[0];
            for (int i = 1; i < 5; ++i)
                if (wbest[i] > best || (wbest[i] == best && wnode[i] < bnode)) {
                    best = wbest[i];
                    bnode = wnode[i];
                    bpos = wpos[i];
                }
            used[bpos] = 1;
            topv[r] = best;
            topi[r] = bnode;
        }
        __syncthreads();
    }
}

__global__ __launch_bounds__(320) void k_mlp(const float* __restrict__ h,
                                             const float* __restrict__ topv,
                                             const int* __restrict__ topi,
                                             const float* __restrict__ mW1, const float* __restrict__ mb1,
                                             const float* __restrict__ mW2, const float* __restrict__ mb2,
                                             const float* __restrict__ mW3, const float* __restrict__ mb3,
                                             float* __restrict__ out) {
    __shared__ float xp[5 * 64], z1[5 * 32], z2[5 * 16];
    int tid = threadIdx.x;
    int k = tid >> 6, f = tid & 63;
    xp[k * 64 + f] = h[(size_t)topi[k] * 64 + f] * tanhf(topv[k]);
    __syncthreads();
    if (tid < 5 * 32) {
        int kk = tid >> 5, j = tid & 31;
        float a = mb1[j];
        for (int f2 = 0; f2 < 64; ++f2) a += xp[kk * 64 + f2] * mW1[f2 * 32 + j];
        z1[tid] = fmaxf(a, 0.f);
    }
    __syncthreads();
    if (tid < 5 * 16) {
        int kk = tid >> 4, j = tid & 15;
        float a = mb2[j];
        for (int f2 = 0; f2 < 32; ++f2) a += z1[kk * 32 + f2] * mW2[f2 * 16 + j];
        z2[tid] = fmaxf(a, 0.f);
    }
    __syncthreads();
    if (tid < 10) {
        int kk = tid >> 1, j = tid & 1;
        float a = mb3[j];
        for (int f2 = 0; f2 < 16; ++f2) a += z2[kk * 16 + f2] * mW3[f2 * 2 + j];
        out[tid] = a;
    }
}

// ---------------- host ----------------

extern "C" void kernel_launch(void* const* d_in, const int* in_sizes, int n_in,
                              void* d_out, int out_size, void* d_ws, size_t ws_size,
                              hipStream_t stream) {
    const float* x = (const float*)d_in[0];
    const int* ei = (const int*)d_in[1];
    const float* eattr = (const float*)d_in[2];
    const float* We1 = (const float*)d_in[4];
    const float* be1 = (const float*)d_in[5];
    const float* preW1 = (const float*)d_in[6];
    const float* preb1 = (const float*)d_in[7];
    const float* postW1 = (const float*)d_in[8];
    const float* postb1 = (const float*)d_in[9];
    const float* linW1 = (const float*)d_in[10];
    const float* linb1 = (const float*)d_in[11];
    const float* bn1g = (const float*)d_in[12];
    const float* bn1b = (const float*)d_in[13];
    const float* We2 = (const float*)d_in[14];
    const float* be2 = (const float*)d_in[15];
    const float* preW2 = (const float*)d_in[16];
    const float* preb2 = (const float*)d_in[17];
    const float* postW2 = (const float*)d_in[18];
    const float* postb2 = (const float*)d_in[19];
    const float* linW2 = (const float*)d_in[20];
    const float* linb2 = (const float*)d_in[21];
    const float* bn2g = (const float*)d_in[22];
    const float* bn2b = (const float*)d_in[23];
    const float* wrel = (const float*)d_in[24];
    const float* pbrel = (const float*)d_in[25];
    const float* wroot = (const float*)d_in[26];
    const float* mW1 = (const float*)d_in[27];
    const float* mb1 = (const float*)d_in[28];
    const float* mW2 = (const float*)d_in[29];
    const float* mb2 = (const float*)d_in[30];
    const float* mW3 = (const float*)d_in[31];
    const float* mb3 = (const float*)d_in[32];
    float* out = (float*)d_out;

    char* w = (char*)d_ws;
    size_t o = 0;
    auto alloc = [&](size_t bytes) {
        size_t r = o;
        o = (o + bytes + 255) & ~(size_t)255;
        return r;
    };
    int* cnt = (int*)(w + alloc((size_t)NN * 4));
    int* offv = (int*)(w + alloc((size_t)(NN + 1) * 4));
    int2* spair = (int2*)(w + alloc((size_t)NE * 8));
    int* part = (int*)(w + alloc((size_t)NN * 4));
    int* bsum = (int*)(w + alloc(256 * 4));
    int* boff = (int*)(w + alloc(260 * 4));
    float* scal = (float*)(w + alloc(64 * 4));
    float* bnst = (float*)(w + alloc(128 * 4));
    float* weff = (float*)(w + alloc((size_t)33 * 64 * 4));
    float* ampv = (float*)(w + alloc((size_t)NN * 4));
    float* attv = (float*)(w + alloc((size_t)NN * 4));
    float* u = (float*)(w + alloc((size_t)NN * 64 * 4));
    float* cvec = (float*)(w + alloc((size_t)NN * 64 * 4));
    float* agg = (float*)(w + alloc((size_t)NN * 256 * 4));
    float* tg0 = (float*)(w + alloc((size_t)NN * 64 * 4));
    float* tg1 = (float*)(w + alloc((size_t)NN * 64 * 4));
    float* tg2 = (float*)(w + alloc((size_t)NN * 64 * 4));
    float* pre = (float*)(w + alloc((size_t)NN * 64 * 4));
    float* h1 = (float*)(w + alloc((size_t)NN * 64 * 4));
    float* h2 = (float*)(w + alloc((size_t)NN * 64 * 4));
    float* s1 = (float*)(w + alloc((size_t)NN * 4));
    float* s2 = (float*)(w + alloc((size_t)NN * 4));
    float* score = (float*)(w + alloc((size_t)NN * 4));
    float* candv = (float*)(w + alloc(320 * 4));
    int* candi = (int*)(w + alloc(320 * 4));
    float* topv = (float*)(w + alloc(16 * 4));
    int* topi = (int*)(w + alloc(16 * 4));
    (void)ws_size; (void)n_in; (void)in_sizes; (void)out_size;

    hipMemsetAsync(cnt, 0, (size_t)NN * 4, stream);
    hipMemsetAsync(scal, 0, 64 * 4, stream);

    int nscan = (NN + 255) / 256;  // 196 <= 256

    k_deg<<<(NE + 255) / 256, 256, 0, stream>>>(ei, cnt);
    k_avglog<<<(NN + 255) / 256, 256, 0, stream>>>(cnt, scal);
    k_scan1<<<nscan, 256, 0, stream>>>(cnt, part, bsum);
    k_scan2<<<1, 256, 0, stream>>>(bsum, boff, scal, nscan);
    k_scan3<<<nscan, 256, 0, stream>>>(part, boff, offv, cnt);
    k_scatter<<<(NE + 255) / 256, 256, 0, stream>>>(ei, offv, cnt, spair);
    k_ampatt<<<(NN + 255) / 256, 256, 0, stream>>>(offv, scal, ampv, attv);

    int ptiles = (NN + 32 * PNP - 1) / (32 * PNP);  // 391

    // ---- layer 1 (G=64 -> 4 col slices via gridDim.y) ----
    k_weff<<<(33 * 64 + 255) / 256, 256, 0, stream>>>(We1, be1, preW1, weff);
    k_uc<<<500, 256, 0, stream>>>(x, preW1, preb1, weff, u, cvec);
    k_edge<<<NN / 4, 256, 0, stream>>>(eattr, offv, spair, u, cvec, weff, agg);
    k_post0<<<dim3(ptiles, 4), 128, 0, stream>>>(x, agg, postW1, 64, postb1, tg0, 0);
    k_postS<<<dim3(ptiles, 4), 128, 0, stream>>>(agg, ampv, postW1 + 320 * 64, 64, tg1, 0);
    k_postS<<<dim3(ptiles, 4), 128, 0, stream>>>(agg, attv, postW1 + 576 * 64, 64, tg2, 0);
    hipMemsetAsync(bnst, 0, 128 * 4, stream);
    k_lin<<<256, 256, 0, stream>>>(tg0, tg1, tg2, linW1, linb1, pre, bnst);
    k_bnrelu<<<(NN * 64) / 256, 256, 0, stream>>>(pre, bnst, bn1g, bn1b, h1);

    // ---- layer 2 (4 towers, each writes cols t*16..t*16+15 of tg0/1/2) ----
    for (int t = 0; t < 4; ++t) {
        const float* pW = preW2 + (size_t)t * 192 * 64;
        const float* pP = postW2 + (size_t)t * 832 * 16;
        k_weff<<<(33 * 64 + 255) / 256, 256, 0, stream>>>(We2, be2, pW, weff);
        k_uc<<<500, 256, 0, stream>>>(h1, pW, preb2 + t * 64, weff, u, cvec);
        k_edge<<<NN / 4, 256, 0, stream>>>(eattr, offv, spair, u, cvec, weff, agg);
        k_post0<<<dim3(ptiles, 1), 128, 0, stream>>>(h1, agg, pP, 16, postb2 + t * 16, tg0, t * 16);
        k_postS<<<dim3(ptiles, 1), 128, 0, stream>>>(agg, ampv, pP + 320 * 16, 16, tg1, t * 16);
        k_postS<<<dim3(ptiles, 1), 128, 0, stream>>>(agg, attv, pP + 576 * 16, 16, tg2, t * 16);
    }
    hipMemsetAsync(bnst, 0, 128 * 4, stream);
    k_lin<<<256, 256, 0, stream>>>(tg0, tg1, tg2, linW2, linb2, pre, bnst);
    k_bnrelu<<<(NN * 64) / 256, 256, 0, stream>>>(pre, bnst, bn2g, bn2b, h2);

    // ---- pooling / topk / mlp ----
    k_pooldots<<<NN / 4, 256, 0, stream>>>(h2, wrel, wroot, s1, s2);
    k_score<<<(NN + 255) / 256, 256, 0, stream>>>(s1, s2, offv, spair, pbrel, score);
    k_top1<<<TOPB, 256, 0, stream>>>(score, candv, candi);
    k_top2<<<1, 320, 0, stream>>>(candv, candi, topv, topi);
    k_mlp<<<1, 320, 0, stream>>>(h2, topv, topi, mW1, mb1, mW2, mb2, mW3, mb3, out);
}

// Round 9
// 994.201 us; speedup vs baseline: 1.4028x; 1.2710x over previous
//
#include <hip/hip_runtime.h>
#include <math.h>
#include <limits.h>

#define NN 50000
#define NE 400000
#define FD 64
#define EDD 32
#define EPSF 1e-5f

// ---------------- degree / sort ----------------

__global__ void k_deg(const int* __restrict__ ei, int* __restrict__ cnt) {
    int e = blockIdx.x * 256 + threadIdx.x;
    if (e < NE) atomicAdd(&cnt[ei[NE + e]], 1);
}

__global__ void k_avglog(const int* __restrict__ cnt, float* __restrict__ scal) {
    int n = blockIdx.x * 256 + threadIdx.x;
    float v = 0.f;
    if (n < NN) v = logf((float)cnt[n] + 1.0f);
    for (int o = 32; o >= 1; o >>= 1) v += __shfl_xor(v, o);
    if ((threadIdx.x & 63) == 0) atomicAdd(&scal[0], v);
}

// 3-phase parallel exclusive scan of cnt -> offv
__global__ __launch_bounds__(256) void k_scan1(const int* __restrict__ cnt,
                                               int* __restrict__ part, int* __restrict__ bsum) {
    __shared__ int buf[256];
    int i = blockIdx.x * 256 + threadIdx.x;
    int v = (i < NN) ? cnt[i] : 0;
    buf[threadIdx.x] = v;
    __syncthreads();
    for (int s = 1; s < 256; s <<= 1) {
        int t = (threadIdx.x >= (unsigned)s) ? buf[threadIdx.x - s] : 0;
        __syncthreads();
        buf[threadIdx.x] += t;
        __syncthreads();
    }
    if (i < NN) part[i] = buf[threadIdx.x] - v;
    if (threadIdx.x == 255) bsum[blockIdx.x] = buf[255];
}

__global__ __launch_bounds__(256) void k_scan2(const int* __restrict__ bsum,
                                               int* __restrict__ boff,
                                               float* __restrict__ scal, int nb) {
    __shared__ int buf[256];
    int tid = threadIdx.x;
    int v = (tid < nb) ? bsum[tid] : 0;
    buf[tid] = v;
    __syncthreads();
    for (int s = 1; s < 256; s <<= 1) {
        int t = (tid >= s) ? buf[tid - s] : 0;
        __syncthreads();
        buf[tid] += t;
        __syncthreads();
    }
    boff[tid] = buf[tid] - v;
    if (tid == nb - 1) boff[nb] = buf[tid];
    if (tid == 0) scal[1] = scal[0] / (float)NN;
}

__global__ void k_scan3(const int* __restrict__ part, const int* __restrict__ boff,
                        int* __restrict__ offv, int* __restrict__ cnt) {
    int i = blockIdx.x * 256 + threadIdx.x;
    if (i < NN) {
        offv[i] = part[i] + boff[blockIdx.x];
        cnt[i] = 0;
    }
    if (i == 0) offv[NN] = boff[gridDim.x];
}

// packs (src_row, edge_id) so k_edge does one uniform load per edge
__global__ void k_scatter(const int* __restrict__ ei, const int* __restrict__ offv,
                          int* __restrict__ cnt, int2* __restrict__ spair) {
    int e = blockIdx.x * 256 + threadIdx.x;
    if (e < NE) {
        int n = ei[NE + e];
        int p = offv[n] + atomicAdd(&cnt[n], 1);
        spair[p] = make_int2(ei[e], e);
    }
}

// amp/att per node
__global__ void k_ampatt(const int* __restrict__ offv, const float* __restrict__ scal,
                         float* __restrict__ ampv, float* __restrict__ attv) {
    int n = blockIdx.x * 256 + threadIdx.x;
    if (n >= NN) return;
    float degf = (float)(offv[n + 1] - offv[n]);
    float d = fmaxf(degf, 1.f);
    float lg = logf(d + 1.f);
    float al = scal[1];
    ampv[n] = lg / al;
    attv[n] = al / lg;
}

// ---------------- per-layer kernels (single tower, T=1) ----------------

__global__ void k_weff(const float* __restrict__ We, const float* __restrict__ be,
                       const float* __restrict__ preW, float* __restrict__ weff) {
    int idx = blockIdx.x * 256 + threadIdx.x;
    if (idx >= 33 * 64) return;
    int k = idx >> 6, g = idx & 63;
    const float* Wee = preW + 128 * 64;
    float acc = 0.f;
    if (k < EDD) {
        for (int f = 0; f < FD; ++f) acc += We[k * FD + f] * Wee[f * FD + g];
    } else {
        for (int f = 0; f < FD; ++f) acc += be[f] * Wee[f * FD + g];
    }
    weff[idx] = acc;
}

__global__ __launch_bounds__(256) void k_uc(const float* __restrict__ xin,
                                            const float* __restrict__ preW,
                                            const float* __restrict__ preb,
                                            const float* __restrict__ weff,
                                            float* __restrict__ u, float* __restrict__ cvec) {
    int g = threadIdx.x & 63;
    int nsub = threadIdx.x >> 6;
    float wU[FD], wC[FD];
#pragma unroll
    for (int f = 0; f < FD; ++f) {
        wC[f] = preW[f * 64 + g];
        wU[f] = preW[(64 + f) * 64 + g];
    }
    float cb = preb[g] + weff[32 * 64 + g];
    __shared__ float xs[4 * 72];
    for (int base = blockIdx.x * 4; base < NN; base += gridDim.x * 4) {
        __syncthreads();
        {
            int i = threadIdx.x;
            int node = base + (i >> 6);
            xs[(i >> 6) * 72 + (i & 63)] = (node < NN) ? xin[(size_t)node * 64 + (i & 63)] : 0.f;
        }
        __syncthreads();
        int n = base + nsub;
        if (n < NN) {
            const float* xv = &xs[nsub * 72];
            float aU = 0.f, aC = 0.f;
#pragma unroll
            for (int f = 0; f < FD; ++f) {
                float x = xv[f];
                aU += x * wU[f];
                aC += x * wC[f];
            }
            u[(size_t)n * 64 + g] = aU;
            cvec[(size_t)n * 64 + g] = aC + cb;
        }
    }
}

// sorted segment reduce, one wave per node (unroll-by-2 scalar-load pipelining)
__global__ __launch_bounds__(256) void k_edge(const float* __restrict__ eattr,
                                              const int* __restrict__ offv,
                                              const int2* __restrict__ spair,
                                              const float* __restrict__ u,
                                              const float* __restrict__ cvec,
                                              const float* __restrict__ weff,
                                              float* __restrict__ agg) {
    int wv = threadIdx.x >> 6, lane = threadIdx.x & 63;
    int n = blockIdx.x * 4 + wv;
    float wreg[32];
#pragma unroll
    for (int k = 0; k < 32; ++k) wreg[k] = weff[k * 64 + lane];
    int p0 = offv[n], p1 = offv[n + 1];
    float sm = 0.f, sq = 0.f, mn = INFINITY, mx = -INFINITY;
    int p = p0;
    for (; p + 1 < p1; p += 2) {
        int2 se0 = spair[p];
        int2 se1 = spair[p + 1];
        int src0 = __builtin_amdgcn_readfirstlane(se0.x);
        int eid0 = __builtin_amdgcn_readfirstlane(se0.y);
        int src1 = __builtin_amdgcn_readfirstlane(se1.x);
        int eid1 = __builtin_amdgcn_readfirstlane(se1.y);
        const float* __restrict__ ea0 = eattr + (size_t)eid0 * EDD;
        const float* __restrict__ ea1 = eattr + (size_t)eid1 * EDD;
        float v0 = u[(size_t)src0 * 64 + lane];
        float v1 = u[(size_t)src1 * 64 + lane];
#pragma unroll
        for (int k = 0; k < 32; ++k) {
            v0 += ea0[k] * wreg[k];
            v1 += ea1[k] * wreg[k];
        }
        sm += v0;
        sq += v0 * v0;
        mn = fminf(mn, v0);
        mx = fmaxf(mx, v0);
        sm += v1;
        sq += v1 * v1;
        mn = fminf(mn, v1);
        mx = fmaxf(mx, v1);
    }
    if (p < p1) {
        int2 se = spair[p];
        int src = __builtin_amdgcn_readfirstlane(se.x);
        int eid = __builtin_amdgcn_readfirstlane(se.y);
        const float* __restrict__ ea = eattr + (size_t)eid * EDD;
        float v = u[(size_t)src * 64 + lane];
#pragma unroll
        for (int k = 0; k < 32; ++k) v += ea[k] * wreg[k];
        sm += v;
        sq += v * v;
        mn = fminf(mn, v);
        mx = fmaxf(mx, v);
    }
    float degf = (float)(p1 - p0);
    float d = fmaxf(degf, 1.f);
    float c = cvec[(size_t)n * 64 + lane];
    float sh = sm + degf * c;
    float mean = sh / d;
    float m2 = (sq + 2.f * c * sm + degf * c * c) / d;
    float var = fmaxf(m2 - mean * mean, 0.f);
    float sd = sqrtf(var + EPSF);
    float mnv = (degf > 0.f) ? mn + c : 0.f;
    float mxv = (degf > 0.f) ? mx + c : 0.f;
    size_t b = (size_t)n * 256 + lane;
    agg[b] = mean;
    agg[b + 64] = mnv;
    agg[b + 128] = mxv;
    agg[b + 192] = sd;
}

// ---------------- post stage: FUSED weight-stationary GEMM ----------------
// tgb[n][cb+sc+c] = bias + x@P0 + agg@P1 + amp*(agg@P2) + att*(agg@P3)
// Whole 832x16 panel staged in LDS (52 KB, 3 blocks/CU). One agg float4 load
// feeds all three regions (48 FMAs). 256 thr: 4-lane col groups, NP=2 nodes.
#define PNP 2

__global__ __launch_bounds__(256) void k_postF(const float* __restrict__ xin,
                                               const float* __restrict__ agg,
                                               const float* __restrict__ ampv,
                                               const float* __restrict__ attv,
                                               const float* __restrict__ P,
                                               int pstride,
                                               const float* __restrict__ pbias,
                                               float* __restrict__ tgb, int cb) {
    __shared__ __align__(16) float wsh[832 * 16];  // 52 KB
    int tid = threadIdx.x;
    int sc = blockIdx.y * 16;
    for (int i = tid; i < 832 * 4; i += 256) {
        int row = i >> 2, c4 = (i & 3) * 4;
        *(float4*)&wsh[row * 16 + c4] = *(const float4*)&P[(size_t)row * pstride + sc + c4];
    }
    __syncthreads();
    int cidx = (tid & 3) * 4;
    int grp = tid >> 2;  // 64 groups
    int nb = blockIdx.x * (64 * PNP) + grp * PNP;
    int nd[PNP];
    float amp[PNP], att[PNP];
#pragma unroll
    for (int k = 0; k < PNP; ++k) {
        nd[k] = (nb + k < NN) ? nb + k : NN - 1;
        amp[k] = ampv[nd[k]];
        att[k] = attv[nd[k]];
    }
    float accA[PNP][4], accB[PNP][4], accC[PNP][4];
#pragma unroll
    for (int k = 0; k < PNP; ++k)
#pragma unroll
        for (int c = 0; c < 4; ++c) { accA[k][c] = 0.f; accB[k][c] = 0.f; accC[k][c] = 0.f; }
    // x region: panel rows 0..63
#pragma unroll 4
    for (int q = 0; q < 64; q += 4) {
        float4 w[4];
#pragma unroll
        for (int r = 0; r < 4; ++r) w[r] = *(const float4*)&wsh[(q + r) * 16 + cidx];
#pragma unroll
        for (int k = 0; k < PNP; ++k) {
            float4 xv = *(const float4*)&xin[(size_t)nd[k] * 64 + q];
            float xa[4] = {xv.x, xv.y, xv.z, xv.w};
#pragma unroll
            for (int r = 0; r < 4; ++r) {
                accA[k][0] += xa[r] * w[r].x;
                accA[k][1] += xa[r] * w[r].y;
                accA[k][2] += xa[r] * w[r].z;
                accA[k][3] += xa[r] * w[r].w;
            }
        }
    }
    // agg regions: rows 64..319 (plain), 320..575 (amp), 576..831 (att)
#pragma unroll 2
    for (int q = 0; q < 256; q += 4) {
        float4 w1[4], w2[4], w3[4];
#pragma unroll
        for (int r = 0; r < 4; ++r) {
            w1[r] = *(const float4*)&wsh[(64 + q + r) * 16 + cidx];
            w2[r] = *(const float4*)&wsh[(320 + q + r) * 16 + cidx];
            w3[r] = *(const float4*)&wsh[(576 + q + r) * 16 + cidx];
        }
#pragma unroll
        for (int k = 0; k < PNP; ++k) {
            float4 av = *(const float4*)&agg[(size_t)nd[k] * 256 + q];
            float aa[4] = {av.x, av.y, av.z, av.w};
#pragma unroll
            for (int r = 0; r < 4; ++r) {
                accA[k][0] += aa[r] * w1[r].x;
                accA[k][1] += aa[r] * w1[r].y;
                accA[k][2] += aa[r] * w1[r].z;
                accA[k][3] += aa[r] * w1[r].w;
                accB[k][0] += aa[r] * w2[r].x;
                accB[k][1] += aa[r] * w2[r].y;
                accB[k][2] += aa[r] * w2[r].z;
                accB[k][3] += aa[r] * w2[r].w;
                accC[k][0] += aa[r] * w3[r].x;
                accC[k][1] += aa[r] * w3[r].y;
                accC[k][2] += aa[r] * w3[r].z;
                accC[k][3] += aa[r] * w3[r].w;
            }
        }
    }
    float4 pbv = *(const float4*)&pbias[sc + cidx];
    float pb[4] = {pbv.x, pbv.y, pbv.z, pbv.w};
#pragma unroll
    for (int k = 0; k < PNP; ++k) {
        int node = nb + k;
        if (node < NN) {
            float4 o;
            o.x = pb[0] + accA[k][0] + amp[k] * accB[k][0] + att[k] * accC[k][0];
            o.y = pb[1] + accA[k][1] + amp[k] * accB[k][1] + att[k] * accC[k][1];
            o.z = pb[2] + accA[k][2] + amp[k] * accB[k][2] + att[k] * accC[k][2];
            o.w = pb[3] + accA[k][3] + amp[k] * accB[k][3] + att[k] * accC[k][3];
            *(float4*)&tgb[(size_t)node * 64 + cb + sc + cidx] = o;
        }
    }
}

// pre = tgb @ linW + linb ; accumulate BN channel sums
__global__ __launch_bounds__(256) void k_lin(const float* __restrict__ tgb,
                                             const float* __restrict__ linW,
                                             const float* __restrict__ linb,
                                             float* __restrict__ pre, float* __restrict__ bn) {
    __shared__ float ts[4 * 72];
    __shared__ float rs[256], rs2[256];
    int c = threadIdx.x & 63, r = threadIdx.x >> 6;
    float w[64];
#pragma unroll
    for (int f = 0; f < 64; ++f) w[f] = linW[f * 64 + c];
    float lb = linb[c];
    float s = 0.f, s2 = 0.f;
    for (int base = blockIdx.x * 4; base < NN; base += gridDim.x * 4) {
        __syncthreads();
        {
            int i = threadIdx.x;
            int node = base + (i >> 6);
            ts[(i >> 6) * 72 + (i & 63)] = (node < NN) ? tgb[(size_t)node * 64 + (i & 63)] : 0.f;
        }
        __syncthreads();
        int n = base + r;
        if (n < NN) {
            const float* tv = &ts[r * 72];
            float a = lb;
#pragma unroll
            for (int f = 0; f < 64; ++f) a += tv[f] * w[f];
            pre[(size_t)n * 64 + c] = a;
            s += a;
            s2 += a * a;
        }
    }
    __syncthreads();
    rs[threadIdx.x] = s;
    rs2[threadIdx.x] = s2;
    __syncthreads();
    if (threadIdx.x < 64) {
        float S = rs[c] + rs[c + 64] + rs[c + 128] + rs[c + 192];
        float S2 = rs2[c] + rs2[c + 64] + rs2[c + 128] + rs2[c + 192];
        atomicAdd(&bn[c], S);
        atomicAdd(&bn[64 + c], S2);
    }
}

__global__ void k_bnrelu(const float* __restrict__ pre, const float* __restrict__ bn,
                         const float* __restrict__ gg, const float* __restrict__ bb,
                         float* __restrict__ h) {
    int i = blockIdx.x * 256 + threadIdx.x;
    if (i >= NN * 64) return;
    int c = i & 63;
    float m = bn[c] * (1.f / (float)NN);
    float v = bn[64 + c] * (1.f / (float)NN) - m * m;
    float x = (pre[i] - m) / sqrtf(v + EPSF) * gg[c] + bb[c];
    h[i] = fmaxf(x, 0.f);
}

// ---------------- pooling / topk / mlp ----------------

__global__ void k_pooldots(const float* __restrict__ h, const float* __restrict__ wrel,
                           const float* __restrict__ wroot, float* __restrict__ s1,
                           float* __restrict__ s2) {
    int wv = threadIdx.x >> 6, lane = threadIdx.x & 63;
    int n = blockIdx.x * 4 + wv;
    if (n >= NN) return;
    float x = h[(size_t)n * 64 + lane];
    float d1 = x * wrel[lane];
    float d2 = x * wroot[lane];
    for (int o = 32; o >= 1; o >>= 1) {
        d1 += __shfl_xor(d1, o);
        d2 += __shfl_xor(d2, o);
    }
    if (lane == 0) { s1[n] = d1; s2[n] = d2; }
}

__global__ void k_score(const float* __restrict__ s1, const float* __restrict__ s2,
                        const int* __restrict__ offv, const int2* __restrict__ spair,
                        const float* __restrict__ pb, float* __restrict__ score) {
    int n = blockIdx.x * 256 + threadIdx.x;
    if (n >= NN) return;
    float sc = pb[0] + s2[n];
    int p1 = offv[n + 1];
    for (int p = offv[n]; p < p1; ++p) sc += s1[spair[p].x];
    score[n] = sc;
}

#define TOPB 64
#define TOPCHUNK 782

__global__ __launch_bounds__(256) void k_top1(const float* __restrict__ score,
                                              float* __restrict__ candv, int* __restrict__ candi) {
    __shared__ float bs[256];
    __shared__ int bi[256];
    __shared__ int chosen[5];
    int b = blockIdx.x;
    int start = b * TOPCHUNK;
    int end = start + TOPCHUNK;
    if (end > NN) end = NN;
    for (int r = 0; r < 5; ++r) {
        float best = -INFINITY;
        int bidx = -1;
        for (int i = start + (int)threadIdx.x; i < end; i += 256) {
            bool skip = false;
            for (int q = 0; q < r; ++q)
                if (chosen[q] == i) skip = true;
            if (!skip) {
                float sv = score[i];
                if (sv > best || (sv == best && (bidx == -1 || i < bidx))) { best = sv; bidx = i; }
            }
        }
        bs[threadIdx.x] = best;
        bi[threadIdx.x] = bidx;
        __syncthreads();
        for (int s = 128; s >= 1; s >>= 1) {
            if ((int)threadIdx.x < s) {
                float s2v = bs[threadIdx.x + s];
                int i2 = bi[threadIdx.x + s];
                float s1v = bs[threadIdx.x];
                int i1 = bi[threadIdx.x];
                if (i2 != -1 && (s2v > s1v || (s2v == s1v && (i1 == -1 || i2 < i1)))) {
                    bs[threadIdx.x] = s2v;
                    bi[threadIdx.x] = i2;
                }
            }
            __syncthreads();
        }
        if (threadIdx.x == 0) {
            candv[b * 5 + r] = bs[0];
            candi[b * 5 + r] = bi[0];
            chosen[r] = bi[0];
        }
        __syncthreads();
    }
}

__global__ __launch_bounds__(320) void k_top2(const float* __restrict__ candv,
                                              const int* __restrict__ candi,
                                              float* __restrict__ topv, int* __restrict__ topi) {
    __shared__ float bs[320];
    __shared__ int bi[320];
    __shared__ int used[320];
    __shared__ float wbest[5];
    __shared__ int wnode[5], wpos[5];
    int tid = threadIdx.x;
    bs[tid] = candv[tid];
    bi[tid] = candi[tid];
    used[tid] = (bi[tid] == -1) ? 1 : 0;
    __syncthreads();
    int wv = tid >> 6, lane = tid & 63;
    for (int r = 0; r < 5; ++r) {
        float s = used[tid] ? -INFINITY : bs[tid];
        int nd = used[tid] ? INT_MAX : bi[tid];
        int pos = tid;
        for (int o = 32; o >= 1; o >>= 1) {
            float s2 = __shfl_xor(s, o);
            int nd2 = __shfl_xor(nd, o);
            int p2 = __shfl_xor(pos, o);
            if (s2 > s || (s2 == s && nd2 < nd)) { s = s2; nd = nd2; pos = p2; }
        }
        if (lane == 0) { wbest[wv] = s; wnode[wv] = nd; wpos[wv] = pos; }
        __syncthreads();
        if (tid == 0) {
            float best = wbest[0];
            int bnode = wnode[0], bpos = wpos[0];
            for (int i = 1; i < 5; ++i)
                if (wbest[i] > best || (wbest[i] == best && wnode[i] < bnode)) {
                    best = wbest[i];
                    bnode = wnode[i];
                    bpos = wpos[i];
                }
            used[bpos] = 1;
            topv[r] = best;
            topi[r] = bnode;
        }
        __syncthreads();
    }
}

__global__ __launch_bounds__(320) void k_mlp(const float* __restrict__ h,
                                             const float* __restrict__ topv,
                                             const int* __restrict__ topi,
                                             const float* __restrict__ mW1, const float* __restrict__ mb1,
                                             const float* __restrict__ mW2, const float* __restrict__ mb2,
                                             const float* __restrict__ mW3, const float* __restrict__ mb3,
                                             float* __restrict__ out) {
    __shared__ float xp[5 * 64], z1[5 * 32], z2[5 * 16];
    int tid = threadIdx.x;
    int k = tid >> 6, f = tid & 63;
    xp[k * 64 + f] = h[(size_t)topi[k] * 64 + f] * tanhf(topv[k]);
    __syncthreads();
    if (tid < 5 * 32) {
        int kk = tid >> 5, j = tid & 31;
        float a = mb1[j];
        for (int f2 = 0; f2 < 64; ++f2) a += xp[kk * 64 + f2] * mW1[f2 * 32 + j];
        z1[tid] = fmaxf(a, 0.f);
    }
    __syncthreads();
    if (tid < 5 * 16) {
        int kk = tid >> 4, j = tid & 15;
        float a = mb2[j];
        for (int f2 = 0; f2 < 32; ++f2) a += z1[kk * 32 + f2] * mW2[f2 * 16 + j];
        z2[tid] = fmaxf(a, 0.f);
    }
    __syncthreads();
    if (tid < 10) {
        int kk = tid >> 1, j = tid & 1;
        float a = mb3[j];
        for (int f2 = 0; f2 < 16; ++f2) a += z2[kk * 16 + f2] * mW3[f2 * 2 + j];
        out[tid] = a;
    }
}

// ---------------- host ----------------

extern "C" void kernel_launch(void* const* d_in, const int* in_sizes, int n_in,
                              void* d_out, int out_size, void* d_ws, size_t ws_size,
                              hipStream_t stream) {
    const float* x = (const float*)d_in[0];
    const int* ei = (const int*)d_in[1];
    const float* eattr = (const float*)d_in[2];
    const float* We1 = (const float*)d_in[4];
    const float* be1 = (const float*)d_in[5];
    const float* preW1 = (const float*)d_in[6];
    const float* preb1 = (const float*)d_in[7];
    const float* postW1 = (const float*)d_in[8];
    const float* postb1 = (const float*)d_in[9];
    const float* linW1 = (const float*)d_in[10];
    const float* linb1 = (const float*)d_in[11];
    const float* bn1g = (const float*)d_in[12];
    const float* bn1b = (const float*)d_in[13];
    const float* We2 = (const float*)d_in[14];
    const float* be2 = (const float*)d_in[15];
    const float* preW2 = (const float*)d_in[16];
    const float* preb2 = (const float*)d_in[17];
    const float* postW2 = (const float*)d_in[18];
    const float* postb2 = (const float*)d_in[19];
    const float* linW2 = (const float*)d_in[20];
    const float* linb2 = (const float*)d_in[21];
    const float* bn2g = (const float*)d_in[22];
    const float* bn2b = (const float*)d_in[23];
    const float* wrel = (const float*)d_in[24];
    const float* pbrel = (const float*)d_in[25];
    const float* wroot = (const float*)d_in[26];
    const float* mW1 = (const float*)d_in[27];
    const float* mb1 = (const float*)d_in[28];
    const float* mW2 = (const float*)d_in[29];
    const float* mb2 = (const float*)d_in[30];
    const float* mW3 = (const float*)d_in[31];
    const float* mb3 = (const float*)d_in[32];
    float* out = (float*)d_out;

    char* w = (char*)d_ws;
    size_t o = 0;
    auto alloc = [&](size_t bytes) {
        size_t r = o;
        o = (o + bytes + 255) & ~(size_t)255;
        return r;
    };
    int* cnt = (int*)(w + alloc((size_t)NN * 4));
    int* offv = (int*)(w + alloc((size_t)(NN + 1) * 4));
    int2* spair = (int2*)(w + alloc((size_t)NE * 8));
    int* part = (int*)(w + alloc((size_t)NN * 4));
    int* bsum = (int*)(w + alloc(256 * 4));
    int* boff = (int*)(w + alloc(260 * 4));
    float* scal = (float*)(w + alloc(64 * 4));
    float* bnst = (float*)(w + alloc(128 * 4));
    float* weff = (float*)(w + alloc((size_t)33 * 64 * 4));
    float* ampv = (float*)(w + alloc((size_t)NN * 4));
    float* attv = (float*)(w + alloc((size_t)NN * 4));
    float* u = (float*)(w + alloc((size_t)NN * 64 * 4));
    float* cvec = (float*)(w + alloc((size_t)NN * 64 * 4));
    float* agg = (float*)(w + alloc((size_t)NN * 256 * 4));
    float* tgb = (float*)(w + alloc((size_t)NN * 64 * 4));
    float* pre = (float*)(w + alloc((size_t)NN * 64 * 4));
    float* h1 = (float*)(w + alloc((size_t)NN * 64 * 4));
    float* h2 = (float*)(w + alloc((size_t)NN * 64 * 4));
    float* s1 = (float*)(w + alloc((size_t)NN * 4));
    float* s2 = (float*)(w + alloc((size_t)NN * 4));
    float* score = (float*)(w + alloc((size_t)NN * 4));
    float* candv = (float*)(w + alloc(320 * 4));
    int* candi = (int*)(w + alloc(320 * 4));
    float* topv = (float*)(w + alloc(16 * 4));
    int* topi = (int*)(w + alloc(16 * 4));
    (void)ws_size; (void)n_in; (void)in_sizes; (void)out_size;

    hipMemsetAsync(cnt, 0, (size_t)NN * 4, stream);
    hipMemsetAsync(scal, 0, 64 * 4, stream);

    int nscan = (NN + 255) / 256;  // 196

    k_deg<<<(NE + 255) / 256, 256, 0, stream>>>(ei, cnt);
    k_avglog<<<(NN + 255) / 256, 256, 0, stream>>>(cnt, scal);
    k_scan1<<<nscan, 256, 0, stream>>>(cnt, part, bsum);
    k_scan2<<<1, 256, 0, stream>>>(bsum, boff, scal, nscan);
    k_scan3<<<nscan, 256, 0, stream>>>(part, boff, offv, cnt);
    k_scatter<<<(NE + 255) / 256, 256, 0, stream>>>(ei, offv, cnt, spair);
    k_ampatt<<<(NN + 255) / 256, 256, 0, stream>>>(offv, scal, ampv, attv);

    int ptiles = (NN + 64 * PNP - 1) / (64 * PNP);  // 391

    // ---- layer 1 (G=64 -> 4 col slices via gridDim.y) ----
    k_weff<<<(33 * 64 + 255) / 256, 256, 0, stream>>>(We1, be1, preW1, weff);
    k_uc<<<500, 256, 0, stream>>>(x, preW1, preb1, weff, u, cvec);
    k_edge<<<NN / 4, 256, 0, stream>>>(eattr, offv, spair, u, cvec, weff, agg);
    k_postF<<<dim3(ptiles, 4), 256, 0, stream>>>(x, agg, ampv, attv, postW1, 64, postb1, tgb, 0);
    hipMemsetAsync(bnst, 0, 128 * 4, stream);
    k_lin<<<256, 256, 0, stream>>>(tgb, linW1, linb1, pre, bnst);
    k_bnrelu<<<(NN * 64) / 256, 256, 0, stream>>>(pre, bnst, bn1g, bn1b, h1);

    // ---- layer 2 (4 towers) ----
    for (int t = 0; t < 4; ++t) {
        const float* pW = preW2 + (size_t)t * 192 * 64;
        const float* pP = postW2 + (size_t)t * 832 * 16;
        k_weff<<<(33 * 64 + 255) / 256, 256, 0, stream>>>(We2, be2, pW, weff);
        k_uc<<<500, 256, 0, stream>>>(h1, pW, preb2 + t * 64, weff, u, cvec);
        k_edge<<<NN / 4, 256, 0, stream>>>(eattr, offv, spair, u, cvec, weff, agg);
        k_postF<<<dim3(ptiles, 1), 256, 0, stream>>>(h1, agg, ampv, attv, pP, 16,
                                                     postb2 + t * 16, tgb, t * 16);
    }
    hipMemsetAsync(bnst, 0, 128 * 4, stream);
    k_lin<<<256, 256, 0, stream>>>(tgb, linW2, linb2, pre, bnst);
    k_bnrelu<<<(NN * 64) / 256, 256, 0, stream>>>(pre, bnst, bn2g, bn2b, h2);

    // ---- pooling / topk / mlp ----
    k_pooldots<<<NN / 4, 256, 0, stream>>>(h2, wrel, wroot, s1, s2);
    k_score<<<(NN + 255) / 256, 256, 0, stream>>>(s1, s2, offv, spair, pbrel, score);
    k_top1<<<TOPB, 256, 0, stream>>>(score, candv, candi);
    k_top2<<<1, 320, 0, stream>>>(candv, candi, topv, topi);
    k_mlp<<<1, 320, 0, stream>>>(h2, topv, topi, mW1, mb1, mW2, mb2, mW3, mb3, out);
}